// Round 11
// baseline (166.192 us; speedup 1.0000x reference)
//
#include <hip/hip_runtime.h>

// Performer causal linear attention (generalized relu kernel), fp32 in/out.
// B=1, H=8, N=1024, D=64, M=128. Chunked formulation, chunk C=128:
//   qp = relu(norm * q @ proj^T) + eps ; kp likewise
//   Z  = cumsum_n kp ; W = qp / Z
//   out_c = W_c @ S0_c + tril(W_c @ Kp_c^T) @ V_c ; S0_c = prefix of Kp^T V
// R11: ONE kernel, zero cross-block deps. Each block (h,c,sub,eh) recomputes
// prior kp via MFMA (proj staged once), accumulates S0 (fp32 MFMA regs) and
// z-base colsums locally, then P1/P2 attention (proven R10 code). 512 blocks
// x 256 thr x 70.7KB LDS -> 2 blocks/CU, all co-resident, single launch.
static constexpr int H = 8, N = 1024, D = 64, M = 128, CHUNK = 128, NC = 8;
static constexpr float EPS = 1e-3f;
static constexpr float NORM = 0.35355339059327373f; // 64^-0.25

typedef __attribute__((ext_vector_type(8))) short short8;
typedef __attribute__((ext_vector_type(4))) float f32x4;

__device__ inline unsigned short f2bf(float x) {
    unsigned u = __float_as_uint(x);
    return (unsigned short)((u + 0x7fffu + ((u >> 16) & 1u)) >> 16);
}
__device__ inline float bf2f(unsigned short u) {
    return __uint_as_float(((unsigned)u) << 16);
}
__device__ inline ushort4 pack4(float4 g) {
    return (ushort4){f2bf(g.x), f2bf(g.y), f2bf(g.z), f2bf(g.w)};
}

// LDS map (shorts):
//   bufKp [128][136]       @ 0      (17408)  own-chunk kp, j rows x m cols
//   projb [128][72]        @ 17408  (9216)   B-operand; retired after q-proj
//     qpl [32][136]        @ 17408  (4352)   own qp (over projb head)
//     s0t [32][136]        @ 17408           S0^T e-half (over qpl, post-zscan)
//     Pb  [32][136]        @ 21760  (4352)   masked P, A-operand
//   kstage [32][72]        @ 26624  (2304)   k/q rows A-operand staging
//   vT  [32][42]           @ 28928  (1344)   v^T e-half B-operand staging
//   kpT [128][42]          @ 30272  (5376)   kp^T A-operand (stride 42: no
//     W [32][136]          @ 30272  (4352)   bank conflict); W overlays later
//   VT  [32][136]          @ 0               v^T for P2b (over bufKp, post-P1)
__global__ __launch_bounds__(256) void k_fused(const float* __restrict__ q,
                                               const float* __restrict__ k,
                                               const float* __restrict__ v,
                                               const float* __restrict__ proj,
                                               float* __restrict__ out) {
    __shared__ __align__(16) short smem[35648]; // 71.3 KB
    short* bufKp = smem;
    short* projb = smem + 17408;
    short* qpl = smem + 17408;
    short* s0t = smem + 17408;
    short* Pb = smem + 21760;
    short* kstage = smem + 26624;
    short* vT = smem + 28928;
    short* kpT = smem + 30272;
    short* W = smem + 30272;
    short* VT = smem;

    const int tid = threadIdx.x;
    const int b = blockIdx.x;
    const int sub = blockIdx.y;
    const int eh = blockIdx.z;
    const int h = b >> 3, c = 7 - (b & 7);
    const int chunkstart = h * N + c * CHUNK;
    const int rowstart = chunkstart + sub * 32;
    const int jrows = (sub + 1) * 32;
    const int gown = c * 4 + sub;
    const int lane = tid & 63, wv = tid >> 6;
    const int rt = wv & 1, js = wv >> 1; // row-tile / col-group per wave
    const int fr = lane & 15, fq = lane >> 4;

    // ---- stage projb once (bf16 B-operand [m][72])
    for (int i4 = tid; i4 < 2048; i4 += 256) {
        int m = i4 >> 4, dq = i4 & 15;
        *(ushort4*)&projb[m * 72 + dq * 4] = pack4(*(const float4*)&proj[i4 * 4]);
    }

    // ---- loop over 32-row groups: prior chunks (G+colsum) then own chunk
    float zacc = 0.f;       // z-base per m (tid<128)
    f32x4 accG[2][2];       // S0 accumulators: mt=wv*2+i, et<2
#pragma unroll
    for (int i = 0; i < 2; i++)
#pragma unroll
        for (int et = 0; et < 2; et++) accG[i][et] = (f32x4){0.f, 0.f, 0.f, 0.f};

    for (int g = 0; g <= gown; ++g) {
        const int gb = h * N + g * 32;
        const bool hasv = (g < c * 4);
        if (g) __syncthreads(); // prior G/colsum reads of kpT,vT done
        // stage k rows -> kstage
        for (int i4 = tid; i4 < 512; i4 += 256) {
            int r = i4 >> 4, dq = i4 & 15;
            float4 gk = *(const float4*)&k[(gb + r) * D + dq * 4];
            gk.x *= NORM; gk.y *= NORM; gk.z *= NORM; gk.w *= NORM;
            *(ushort4*)&kstage[r * 72 + dq * 4] = pack4(gk);
        }
        if (hasv) {
            int r = tid >> 3, e4 = (tid & 7) * 4;
            float4 gv = *(const float4*)&v[(gb + r) * D + eh * 32 + e4];
            vT[(e4 + 0) * 42 + r] = (short)f2bf(gv.x);
            vT[(e4 + 1) * 42 + r] = (short)f2bf(gv.y);
            vT[(e4 + 2) * 42 + r] = (short)f2bf(gv.z);
            vT[(e4 + 3) * 42 + r] = (short)f2bf(gv.w);
        }
        __syncthreads();
        // proj MFMA: 32 rows x 128 m, K=64. Wave (rt, js): 4 m-tiles.
        f32x4 accp[4];
#pragma unroll
        for (int i = 0; i < 4; i++) accp[i] = (f32x4){0.f, 0.f, 0.f, 0.f};
#pragma unroll
        for (int kt = 0; kt < 2; kt++) {
            short8 a = *(const short8*)&kstage[(16 * rt + fr) * 72 + kt * 32 + fq * 8];
#pragma unroll
            for (int i = 0; i < 4; i++) {
                const int mt = js * 4 + i;
                short8 bb =
                    *(const short8*)&projb[(16 * mt + fr) * 72 + kt * 32 + fq * 8];
                accp[i] = __builtin_amdgcn_mfma_f32_16x16x32_bf16(a, bb, accp[i], 0, 0, 0);
            }
        }
        // epilogue: relu+eps -> kpT (if needed) and bufKp (own chunk)
        const bool own = (g >= c * 4);
        const int grow = (g - c * 4) * 32;
#pragma unroll
        for (int i = 0; i < 4; i++) {
            const int mt = js * 4 + i;
#pragma unroll
            for (int reg = 0; reg < 4; reg++) {
                const int r = 16 * rt + fq * 4 + reg;
                const int m = 16 * mt + fr;
                unsigned short bv = f2bf(fmaxf(accp[i][reg], 0.f) + EPS);
                if (g < gown) kpT[m * 42 + r] = (short)bv;
                if (own) bufKp[(grow + r) * 136 + m] = (short)bv;
            }
        }
        __syncthreads();
        // G accumulation (prior chunks only) + colsum for z-base
        if (hasv) {
#pragma unroll
            for (int i = 0; i < 2; i++) {
                const int mt = wv * 2 + i;
                short8 a = *(const short8*)&kpT[(16 * mt + fr) * 42 + fq * 8];
#pragma unroll
                for (int et = 0; et < 2; et++) {
                    short8 bb = *(const short8*)&vT[(16 * et + fr) * 42 + fq * 8];
                    accG[i][et] =
                        __builtin_amdgcn_mfma_f32_16x16x32_bf16(a, bb, accG[i][et], 0, 0, 0);
                }
            }
        }
        if (g < gown && tid < 128) {
            float ks = 0.f;
#pragma unroll 8
            for (int r = 0; r < 32; r++) ks += bf2f((unsigned short)kpT[tid * 42 + r]);
            zacc += ks;
        }
    }

    // ---- q-proj for own 32 rows (kstage rewrite fenced by last barrier)
    for (int i4 = tid; i4 < 512; i4 += 256) {
        int r = i4 >> 4, dq = i4 & 15;
        float4 gq = *(const float4*)&q[(rowstart + r) * D + dq * 4];
        gq.x *= NORM; gq.y *= NORM; gq.z *= NORM; gq.w *= NORM;
        *(ushort4*)&kstage[r * 72 + dq * 4] = pack4(gq);
    }
    __syncthreads();
    f32x4 accq[4];
#pragma unroll
    for (int i = 0; i < 4; i++) accq[i] = (f32x4){0.f, 0.f, 0.f, 0.f};
#pragma unroll
    for (int kt = 0; kt < 2; kt++) {
        short8 a = *(const short8*)&kstage[(16 * rt + fr) * 72 + kt * 32 + fq * 8];
#pragma unroll
        for (int i = 0; i < 4; i++) {
            const int mt = js * 4 + i;
            short8 bb = *(const short8*)&projb[(16 * mt + fr) * 72 + kt * 32 + fq * 8];
            accq[i] = __builtin_amdgcn_mfma_f32_16x16x32_bf16(a, bb, accq[i], 0, 0, 0);
        }
    }
    __syncthreads(); // all projb reads done -> qpl may overwrite
#pragma unroll
    for (int i = 0; i < 4; i++) {
        const int mt = js * 4 + i;
#pragma unroll
        for (int reg = 0; reg < 4; reg++) {
            const int r = 16 * rt + fq * 4 + reg;
            const int m = 16 * mt + fr;
            qpl[r * 136 + m] = (short)f2bf(fmaxf(accq[i][reg], 0.f) + EPS);
        }
    }
    __syncthreads(); // qpl visible; bufKp complete

    // ---- z-scan: W = qp / Z (serial 32, LDS-sourced)
    if (tid < 128) {
        const int m = tid;
        float z = zacc;
#pragma unroll 8
        for (int r = 0; r < 32; r++) {
            z += bf2f((unsigned short)bufKp[(sub * 32 + r) * 136 + m]);
            W[r * 136 + m] = (short)f2bf(
                bf2f((unsigned short)qpl[r * 136 + m]) * __builtin_amdgcn_rcpf(z));
        }
    }
    __syncthreads(); // W visible

    // ---- P1: A = tril(W @ Kp^T). Wave (rt, js): jt = js*4 + jl.
    const int jtmax = 2 * sub + 2;
    f32x4 acc1[4];
#pragma unroll
    for (int jl = 0; jl < 4; jl++) acc1[jl] = (f32x4){0.f, 0.f, 0.f, 0.f};
#pragma unroll
    for (int kt = 0; kt < 4; kt++) {
        short8 a = *(const short8*)&W[(16 * rt + fr) * 136 + kt * 32 + fq * 8];
#pragma unroll
        for (int jl = 0; jl < 4; jl++) {
            const int jt = js * 4 + jl;
            if (jt < jtmax) {
                short8 bb =
                    *(const short8*)&bufKp[(16 * jt + fr) * 136 + kt * 32 + fq * 8];
                acc1[jl] =
                    __builtin_amdgcn_mfma_f32_16x16x32_bf16(a, bb, acc1[jl], 0, 0, 0);
            }
        }
    }
    __syncthreads(); // bufKp reads done (VT overwrite); qpl dead (s0t)

    // ---- Pb (masked) ; s0t from accG ; VT staging
#pragma unroll
    for (int jl = 0; jl < 4; jl++) {
        const int jt = js * 4 + jl;
        if (jt < jtmax) {
            const int j = 16 * jt + fr;
#pragma unroll
            for (int reg = 0; reg < 4; reg++) {
                const int nloc = 16 * rt + fq * 4 + reg;
                float val = (j <= sub * 32 + nloc) ? acc1[jl][reg] : 0.f;
                Pb[nloc * 136 + j] = (short)f2bf(val);
            }
        }
    }
#pragma unroll
    for (int i = 0; i < 2; i++) {
        const int mt = wv * 2 + i;
#pragma unroll
        for (int et = 0; et < 2; et++)
#pragma unroll
            for (int reg = 0; reg < 4; reg++) {
                const int m = 16 * mt + fq * 4 + reg;
                const int el = 16 * et + fr;
                s0t[el * 136 + m] = (short)f2bf(accG[i][et][reg]);
            }
    }
    for (int i = tid; i < jrows * 8; i += 256) {
        int j = i >> 3, e4 = (i & 7) * 4;
        float4 gv = *(const float4*)&v[(chunkstart + j) * D + eh * 32 + e4];
        VT[(e4 + 0) * 136 + j] = (short)f2bf(gv.x);
        VT[(e4 + 1) * 136 + j] = (short)f2bf(gv.y);
        VT[(e4 + 2) * 136 + j] = (short)f2bf(gv.z);
        VT[(e4 + 3) * 136 + j] = (short)f2bf(gv.w);
    }
    __syncthreads();

    // ---- P2: out = W @ S0 (K=128) + P @ V (K causal). Wave (rt, et=js).
    f32x4 acc2 = (f32x4){0.f, 0.f, 0.f, 0.f};
#pragma unroll
    for (int kt = 0; kt < 4; kt++) {
        short8 a = *(const short8*)&W[(16 * rt + fr) * 136 + kt * 32 + fq * 8];
        short8 bb = *(const short8*)&s0t[(16 * js + fr) * 136 + kt * 32 + fq * 8];
        acc2 = __builtin_amdgcn_mfma_f32_16x16x32_bf16(a, bb, acc2, 0, 0, 0);
    }
    const int ktmax = sub + 1;
    for (int kt = 0; kt < ktmax; kt++) {
        short8 a = *(const short8*)&Pb[(16 * rt + fr) * 136 + kt * 32 + fq * 8];
        short8 bb = *(const short8*)&VT[(16 * js + fr) * 136 + kt * 32 + fq * 8];
        acc2 = __builtin_amdgcn_mfma_f32_16x16x32_bf16(a, bb, acc2, 0, 0, 0);
    }

    // ---- epilogue
#pragma unroll
    for (int reg = 0; reg < 4; reg++) {
        out[(rowstart + 16 * rt + fq * 4 + reg) * D + eh * 32 + 16 * js + fr] =
            acc2[reg];
    }
}

extern "C" void kernel_launch(void* const* d_in, const int* in_sizes, int n_in,
                              void* d_out, int out_size, void* d_ws, size_t ws_size,
                              hipStream_t stream) {
    const float* q = (const float*)d_in[0];
    const float* k = (const float*)d_in[1];
    const float* v = (const float*)d_in[2];
    const float* proj = (const float*)d_in[3];
    float* out = (float*)d_out;
    (void)d_ws; (void)ws_size; // no workspace needed: zero global intermediates

    k_fused<<<dim3(H * NC, 4, 2), 256, 0, stream>>>(q, k, v, proj, out);
}

// Round 12
// 88.100 us; speedup vs baseline: 1.8864x; 1.8864x over previous
//
#include <hip/hip_runtime.h>

// Performer causal linear attention (generalized relu kernel), fp32 in/out.
// B=1, H=8, N=1024, D=64, M=128. Chunked formulation, chunk C=128:
//   qp = relu(norm * q @ proj^T) + eps ; kp likewise
//   Z  = cumsum_n kp ; W = qp / Z
//   out_c = W_c @ S0_c + tril(W_c @ Kp_c^T) @ V_c ; S0_c = prefix of Kp^T V
// R12: revert to R9 (best: 89.7/89.8); K2 surgical fixes only:
//  (1) causal Kp staging (only (sub+1)*32 rows), (2) V prefetched to regs at
//  kernel start and written to LDS post-P1 (latency hidden), (3) 4 barriers.
static constexpr int H = 8, N = 1024, D = 64, M = 128, CHUNK = 128, NC = 8;
static constexpr float EPS = 1e-3f;
static constexpr float NORM = 0.35355339059327373f; // 64^-0.25

typedef __attribute__((ext_vector_type(8))) short short8;
typedef __attribute__((ext_vector_type(4))) float f32x4;

__device__ inline unsigned short f2bf(float x) {
    unsigned u = __float_as_uint(x);
    return (unsigned short)((u + 0x7fffu + ((u >> 16) & 1u)) >> 16);
}
__device__ inline float bf2f(unsigned short u) {
    return __uint_as_float(((unsigned)u) << 16);
}
__device__ inline ushort4 pack4(float4 g) {
    return (ushort4){f2bf(g.x), f2bf(g.y), f2bf(g.z), f2bf(g.w)};
}

// -------- K1: qpb/kpb = bf16(relu(norm x @ proj^T)+eps), Gpb, kpart.
// grid (32 rblk, 8 h), 512 thr. One block: 32 rows of BOTH q and k.
// (identical to R9)
__global__ __launch_bounds__(512) void k_projg(const float* __restrict__ q,
                                               const float* __restrict__ k,
                                               const float* __restrict__ proj,
                                               const float* __restrict__ v,
                                               unsigned short* __restrict__ qpb,
                                               unsigned short* __restrict__ kpb,
                                               unsigned short* __restrict__ Gpb,
                                               float* __restrict__ kpart) {
    __shared__ __align__(16) short smem[30208]; // 60.4 KB
    short* projb = smem;         // [m 128][72] B-operand
    short* xb = smem + 9216;     // [r 64][72] A-operand (q rows 0-31, k 32-63)
    short* obuf = smem + 13824;  // [64][136] out tile / later [128][68] G
    short* kpT = smem + 22528;   // [m 128][40] A-operand for G
    short* vT = smem + 27648;    // [e 64][40] B-operand for G
    const int tid = threadIdx.x;
    const int rblk = blockIdx.x;
    const int h = blockIdx.y;
    const int rowbase = h * N + rblk * 32;
    const int lane = tid & 63, wv = tid >> 6;
    const int rt = wv & 3, mh = wv >> 2;
    const int fr = lane & 15, fq = lane >> 4;

    for (int i4 = tid; i4 < 2048; i4 += 512) {
        int m = i4 >> 4, dq = i4 & 15;
        *(ushort4*)&projb[m * 72 + dq * 4] = pack4(*(const float4*)&proj[i4 * 4]);
    }
    {
        int r = tid >> 4, dq = tid & 15;
        float4 g = *(const float4*)&q[(rowbase + r) * D + dq * 4];
        g.x *= NORM; g.y *= NORM; g.z *= NORM; g.w *= NORM;
        *(ushort4*)&xb[r * 72 + dq * 4] = pack4(g);
        float4 gk = *(const float4*)&k[(rowbase + r) * D + dq * 4];
        gk.x *= NORM; gk.y *= NORM; gk.z *= NORM; gk.w *= NORM;
        *(ushort4*)&xb[(32 + r) * 72 + dq * 4] = pack4(gk);
        int rv = tid & 31, e4 = (tid >> 5) * 4;
        float4 gv = *(const float4*)&v[(rowbase + rv) * D + e4];
        vT[(e4 + 0) * 40 + rv] = (short)f2bf(gv.x);
        vT[(e4 + 1) * 40 + rv] = (short)f2bf(gv.y);
        vT[(e4 + 2) * 40 + rv] = (short)f2bf(gv.z);
        vT[(e4 + 3) * 40 + rv] = (short)f2bf(gv.w);
    }
    __syncthreads();

    f32x4 accp[4];
#pragma unroll
    for (int i = 0; i < 4; i++) accp[i] = (f32x4){0.f, 0.f, 0.f, 0.f};
#pragma unroll
    for (int kt = 0; kt < 2; kt++) {
        short8 a = *(const short8*)&xb[(16 * rt + fr) * 72 + kt * 32 + fq * 8];
#pragma unroll
        for (int i = 0; i < 4; i++) {
            const int mt = mh * 4 + i;
            short8 bb = *(const short8*)&projb[(16 * mt + fr) * 72 + kt * 32 + fq * 8];
            accp[i] = __builtin_amdgcn_mfma_f32_16x16x32_bf16(a, bb, accp[i], 0, 0, 0);
        }
    }
#pragma unroll
    for (int i = 0; i < 4; i++) {
        const int mt = mh * 4 + i;
#pragma unroll
        for (int reg = 0; reg < 4; reg++) {
            const int r = 16 * rt + fq * 4 + reg;
            const int m = 16 * mt + fr;
            unsigned short bv = f2bf(fmaxf(accp[i][reg], 0.f) + EPS);
            obuf[r * 136 + m] = (short)bv;
            if (rt >= 2) kpT[m * 40 + (r - 32)] = (short)bv;
        }
    }
    __syncthreads();

    for (int i = tid; i < 2048; i += 512) {
        int r = i >> 5, cu = i & 31;
        ushort4 val = *(const ushort4*)&obuf[r * 136 + cu * 4];
        unsigned short* g = (r < 32) ? &qpb[(rowbase + r) * M + cu * 4]
                                     : &kpb[(rowbase + r - 32) * M + cu * 4];
        *(ushort4*)g = val;
    }
    const int gb = h * 32 + rblk;
    if (tid < 128) {
        float ks = 0.f;
#pragma unroll 8
        for (int r = 0; r < 32; r++) ks += bf2f((unsigned short)kpT[tid * 40 + r]);
        kpart[gb * M + tid] = ks;
    }
    __syncthreads();

    f32x4 gacc[4];
#pragma unroll
    for (int et = 0; et < 4; et++) gacc[et] = (f32x4){0.f, 0.f, 0.f, 0.f};
    {
        short8 a = *(const short8*)&kpT[(16 * wv + fr) * 40 + fq * 8];
#pragma unroll
        for (int et = 0; et < 4; et++) {
            short8 bb = *(const short8*)&vT[(16 * et + fr) * 40 + fq * 8];
            gacc[et] = __builtin_amdgcn_mfma_f32_16x16x32_bf16(a, bb, gacc[et], 0, 0, 0);
        }
    }
#pragma unroll
    for (int et = 0; et < 4; et++)
#pragma unroll
        for (int reg = 0; reg < 4; reg++) {
            const int m = 16 * wv + fq * 4 + reg;
            obuf[m * 68 + 16 * et + fr] = (short)f2bf(gacc[et][reg]);
        }
    __syncthreads();
    for (int i = tid; i < 2048; i += 512) {
        int m = i >> 4, e4 = (i & 15) * 4;
        *(ushort4*)&Gpb[(gb * M + m) * D + e4] = *(const ushort4*)&obuf[m * 68 + e4];
    }
}

// -------- K2: grid (64, 4 subs), 512 thr. Per block: 32 output rows x 64 e.
// R12: causal Kp staging; V prefetched to regs; 4 barriers.
__global__ __launch_bounds__(512) void k_attn(const unsigned short* __restrict__ qpb,
                                              const unsigned short* __restrict__ kpb,
                                              const float* __restrict__ kpart,
                                              const unsigned short* __restrict__ Gpb,
                                              const float* __restrict__ v,
                                              float* __restrict__ out) {
    __shared__ __align__(16) short smem[26112]; // 52.2 KB
    short* bufA = smem;         // W [32][136]
    short* bufB = smem + 4352;  // Kp [<=128][136]; post-P1: S0T[64][136] + VT[64][136]
    short* bufC = smem + 21760; // qp [32][136] then Pb [32][136]
    short* s0t = bufB;
    short* vT = bufB + 8704;
    const int tid = threadIdx.x;
    const int b = blockIdx.x;
    const int sub = blockIdx.y;
    const int h = b >> 3, c = 7 - (b & 7); // heavy chunks first
    const int chunkbase = h * N + c * CHUNK;
    const int rowstart = chunkbase + sub * 32;
    const int jrows = (sub + 1) * 32; // causal row count
    const int lane = tid & 63, wv = tid >> 6;
    const int rt = wv & 1, js = wv >> 1;
    const int fr = lane & 15, fq = lane >> 4;

    // ---- prefetch V rows (full chunk, 4 float4/thread) into regs
    float4 vpre[4];
#pragma unroll
    for (int t = 0; t < 4; t++) {
        const int i = tid + t * 512;
        const int j = i >> 4, e4 = (i & 15) * 4;
        vpre[t] = *(const float4*)&v[(chunkbase + j) * D + e4];
    }

    // ---- stage Kp causal rows + own qp rows (coalesced uint loads)
    {
        const unsigned int* src = (const unsigned int*)kpb;
        for (int i = tid; i < jrows * 64; i += 512) {
            int j = i >> 6, mu = i & 63;
            ((unsigned int*)&bufB[j * 136])[mu] = src[(chunkbase + j) * 64 + mu];
        }
        const unsigned int* srcq = (const unsigned int*)qpb;
        for (int i = tid; i < 2048; i += 512) {
            int r = i >> 6, mu = i & 63;
            ((unsigned int*)&bufC[r * 136])[mu] = srcq[(rowstart + r) * 64 + mu];
        }
    }
    __syncthreads(); // (1)

    // ---- z-scan (tid<128, LDS-sourced) + S0 chunk-prefix regs (all)
    if (tid < 128) {
        const int m = tid;
        float z = 0.f;
        const int send = c * 4 + sub;
        for (int s = 0; s < send; s++) z += kpart[(h * 32 + s) * M + m];
#pragma unroll 8
        for (int r = 0; r < 32; r++) {
            z += bf2f((unsigned short)bufB[(sub * 32 + r) * 136 + m]);
            bufA[r * 136 + m] = (short)f2bf(
                bf2f((unsigned short)bufC[r * 136 + m]) * __builtin_amdgcn_rcpf(z));
        }
    }
    float s0r[16];
#pragma unroll
    for (int j = 0; j < 16; j++) s0r[j] = 0.f;
    for (int cp = 0; cp < c; cp++) {
#pragma unroll
        for (int p = 0; p < 4; p++) {
            const short* gsrc =
                (const short*)&Gpb[(h * 32 + cp * 4 + p) * (M * D) + tid * 16];
            short8 g0 = *(const short8*)&gsrc[0];
            short8 g1 = *(const short8*)&gsrc[8];
#pragma unroll
            for (int j = 0; j < 8; j++) {
                s0r[j] += bf2f((unsigned short)g0[j]);
                s0r[8 + j] += bf2f((unsigned short)g1[j]);
            }
        }
    }
    __syncthreads(); // (2) W ready; qp consumed

    // ---- P1: A = tril(W @ Kp^T). Wave (rt, js): jt = 2*js + jl.
    const int jtmax = 2 * sub + 2;
    f32x4 acc1[2];
    acc1[0] = (f32x4){0.f, 0.f, 0.f, 0.f};
    acc1[1] = (f32x4){0.f, 0.f, 0.f, 0.f};
#pragma unroll
    for (int kt = 0; kt < 4; kt++) {
        short8 a = *(const short8*)&bufA[(16 * rt + fr) * 136 + kt * 32 + fq * 8];
#pragma unroll
        for (int jl = 0; jl < 2; jl++) {
            const int jt = 2 * js + jl;
            if (jt < jtmax) {
                short8 bb =
                    *(const short8*)&bufB[(16 * jt + fr) * 136 + kt * 32 + fq * 8];
                acc1[jl] =
                    __builtin_amdgcn_mfma_f32_16x16x32_bf16(a, bb, acc1[jl], 0, 0, 0);
            }
        }
    }
    __syncthreads(); // (3) Kp reads done -> bufB reusable; bufC free

    // ---- Pb (masked) -> bufC ; S0T from regs ; VT from prefetched regs
#pragma unroll
    for (int jl = 0; jl < 2; jl++) {
        const int jt = 2 * js + jl;
        if (jt < jtmax) {
            const int j = 16 * jt + fr;
#pragma unroll
            for (int reg = 0; reg < 4; reg++) {
                const int nloc = 16 * rt + fq * 4 + reg;
                float val = (j <= sub * 32 + nloc) ? acc1[jl][reg] : 0.f;
                bufC[nloc * 136 + j] = (short)f2bf(val);
            }
        }
    }
    {
        const int m = tid >> 2;
        const int ebase = (tid & 3) * 16;
#pragma unroll
        for (int j = 0; j < 16; j++)
            s0t[(ebase + j) * 136 + m] = (short)f2bf(s0r[j]);
    }
#pragma unroll
    for (int t = 0; t < 4; t++) {
        const int i = tid + t * 512;
        const int j = i >> 4, e4 = (i & 15) * 4;
        vT[(e4 + 0) * 136 + j] = (short)f2bf(vpre[t].x);
        vT[(e4 + 1) * 136 + j] = (short)f2bf(vpre[t].y);
        vT[(e4 + 2) * 136 + j] = (short)f2bf(vpre[t].z);
        vT[(e4 + 3) * 136 + j] = (short)f2bf(vpre[t].w);
    }
    __syncthreads(); // (4)

    // ---- P2a: out = W @ S0 (K=128); wave (rt, et=js)
    f32x4 acc2 = (f32x4){0.f, 0.f, 0.f, 0.f};
#pragma unroll
    for (int kt = 0; kt < 4; kt++) {
        short8 a = *(const short8*)&bufA[(16 * rt + fr) * 136 + kt * 32 + fq * 8];
        short8 bb = *(const short8*)&s0t[(16 * js + fr) * 136 + kt * 32 + fq * 8];
        acc2 = __builtin_amdgcn_mfma_f32_16x16x32_bf16(a, bb, acc2, 0, 0, 0);
    }
    // ---- P2b: out += P @ V (K limited to (sub+1)*32 by causality)
    const int ktmax = sub + 1;
    for (int kt = 0; kt < ktmax; kt++) {
        short8 a = *(const short8*)&bufC[(16 * rt + fr) * 136 + kt * 32 + fq * 8];
        short8 bb = *(const short8*)&vT[(16 * js + fr) * 136 + kt * 32 + fq * 8];
        acc2 = __builtin_amdgcn_mfma_f32_16x16x32_bf16(a, bb, acc2, 0, 0, 0);
    }

    // ---- epilogue
#pragma unroll
    for (int reg = 0; reg < 4; reg++) {
        out[(rowstart + 16 * rt + fq * 4 + reg) * D + 16 * js + fr] = acc2[reg];
    }
}

extern "C" void kernel_launch(void* const* d_in, const int* in_sizes, int n_in,
                              void* d_out, int out_size, void* d_ws, size_t ws_size,
                              hipStream_t stream) {
    const float* q = (const float*)d_in[0];
    const float* k = (const float*)d_in[1];
    const float* v = (const float*)d_in[2];
    const float* proj = (const float*)d_in[3];
    float* out = (float*)d_out;

    // workspace: kpart 128KB fp32; qpb/kpb 2MB bf16; Gpb 4MB bf16
    float* ws = (float*)d_ws;
    float* kpart = ws;                                           // H*32*M
    unsigned short* qpb = (unsigned short*)(kpart + H * 32 * M); // H*N*M
    unsigned short* kpb = qpb + H * N * M;                       // H*N*M
    unsigned short* Gpb = kpb + H * N * M;                       // H*32*M*D

    k_projg<<<dim3(32, H), 512, 0, stream>>>(q, k, proj, v, qpb, kpb, Gpb,
                                             kpart);
    k_attn<<<dim3(H * NC, 4), 512, 0, stream>>>(qpb, kpb, kpart, Gpb, v, out);
}